// Round 16
// baseline (90.317 us; speedup 1.0000x reference)
//
#include <hip/hip_runtime.h>
#include <hip/hip_bf16.h>
#include <math.h>

// EfficientMixedScoreMultiHeadAttentionLayer — round 16 (= r15 + 2 fixes).
// (1) mixed: GEMM2 accumulator split 2-way (even/odd k2) — the 16-deep
//     dependent-MFMA C-accumulate chain was the longest serial path at ~4
//     waves/SIMD; depth 16->8, independent MFMA streams 2->4 per wave.
// (2) vtpad: 49152 scattered 2B stores -> 6144 x f16x8 stores (PREP 202->34).
// B=8, R=C=200, E=256, H=16, D=16, MS_HID=32, SDIMS=2.

namespace {
constexpr int kB = 8, kH = 16;
constexpr float kNEG = -1e9f;
constexpr float kCLIP = 10.f;

typedef _Float16 f16x8 __attribute__((ext_vector_type(8)));
typedef float f32x4 __attribute__((ext_vector_type(4)));
typedef int i32x4 __attribute__((ext_vector_type(4)));
typedef unsigned short us8 __attribute__((ext_vector_type(8)));
typedef unsigned int u32;

// ---- input stream region boundaries (element index over concatenated inputs)
constexpr int B1 = 409600;    // x2
constexpr int B2 = 819200;    // cost
constexpr int B3 = 1139200;   // Wqv1
constexpr int B4 = 1270272;   // Wkv2
constexpr int B5 = 1401344;   // L1   (handled by prep branch)
constexpr int B8 = 1425936;   // o1w
constexpr int B9 = 1491472;   // o2w
constexpr int CVT_TOTAL = 1557008;
constexpr int CVT_BLOCKS = 761;   // ceil(CVT_TOTAL/8/256)
constexpr int PREP_BLOCKS = 34;   // 1024 w1g01 + 1024 l2pack + 512 betap + 6144 vtpad = 8704

// ---- ws: flags then f16 heap
constexpr int FLAGS = 0;      // 16 ints
constexpr int F32_END = 16;
// f16 element offsets from hb base
constexpr int QH = 0;
constexpr int KH = 409600;
constexpr int W1G01 = 819200;         // 32 tiles x 32 lanes x 8 (dense g0/g1)
constexpr int BETAP = 827392;         // 32 tiles x 16
constexpr int L2PACK = 835584;        // 16 steps x 64 lanes x 8
constexpr int MIXA = 843776;          // 8b x 13 x 13 x 16h x 256 = 5,537,792
constexpr int MIXB = 6381568;         // 5,537,792
constexpr int X1H = 11919360;         // 409600
constexpr int X2H = 12328960;         // 409600
constexpr int WQH = 12738560;         // 131072
constexpr int WKH = 12869632;         // 131072
constexpr int VT1 = 13000704;         // 2048 rows x 224
constexpr int VT2 = 13459456;         // 2048 rows x 224
constexpr int WV1 = 13918208;         // 409600  [b][r][256]
constexpr int WV2 = 14327808;         // 409600  [b][c][256]
constexpr int O1H = 14737408;         // 65536
constexpr int O2H = 14802944;         // 65536
constexpr int COSTH = 14868480;       // 320000
constexpr size_t F16_END = 15188480;
constexpr size_t WS_NEED = (size_t)F32_END * 4 + F16_END * 2;  // ~30.4 MB

__device__ inline _Float16 f2h(float v) { return (_Float16)v; }
__device__ inline u32 pack2(float lo, float hi) {
  return (u32)__builtin_bit_cast(unsigned short, (_Float16)lo) |
         ((u32)__builtin_bit_cast(unsigned short, (_Float16)hi) << 16);
}
__device__ inline u32 pkrtz(float lo, float hi) {
  return __builtin_bit_cast(u32, __builtin_amdgcn_cvt_pkrtz(lo, hi));
}
__device__ inline float fast_tanh(float x) {
  float t = __expf(2.f * x);
  return (t - 1.f) * __builtin_amdgcn_rcpf(t + 1.f);
}
__device__ inline float rdraw(const void* s, int idx, int isbf) {
  return isbf ? __uint_as_float(((u32)((const unsigned short*)s)[idx]) << 16)
              : ((const float*)s)[idx];
}

// ---- cvt (x8 vectorized) + dtype detect + weight pack + vt pad, one kernel --
__global__ __launch_bounds__(256) void cvtprep_kernel(
    const void* s0, const void* s1, const void* s2, const void* s3,
    const void* s4, const void* s5, const void* s6, const void* s7,
    const void* s8, const void* s9, const unsigned char* __restrict__ mb,
    _Float16* __restrict__ hb, int* __restrict__ flags) {
  const int lane = threadIdx.x & 63;
  int bad = 0;
  const unsigned short* xp = (const unsigned short*)s0;
#pragma unroll
  for (int j = 0; j < 4; ++j) {
    float f = __uint_as_float(((u32)xp[lane * 4 + j]) << 16);
    if (!(fabsf(f) <= 1000.f)) bad = 1;  // catches NaN/inf too
  }
  const int isbf = __ballot(bad) ? 0 : 1;
  if (blockIdx.x == 0 && threadIdx.x < 64) {
    int nz = 0;
    for (int i = lane; i < 512; i += 64)
      if ((i & 3) && mb[i]) nz = 1;
    unsigned long long vn = __ballot(nz);
    if (lane == 0) { flags[0] = isbf; flags[1] = vn ? 1 : 4; }
  }

  if (blockIdx.x < CVT_BLOCKS) {
    int i = (blockIdx.x * 256 + threadIdx.x) * 8;
    if (i >= CVT_TOTAL) return;
    const void* src;
    int off, hdst;
    if (i < B2) {
      if (i < B1) { src = s0; off = i; hdst = X1H + off; }
      else { src = s1; off = i - B1; hdst = X2H + off; }
    } else if (i < B4) {
      if (i < B3) { src = s2; off = i - B2; hdst = COSTH + off; }
      else { src = s3; off = i - B3; hdst = WQH + off; }
    } else if (i < B5) {
      src = s4; off = i - B4; hdst = WKH + off;
    } else if (i < B8) {
      return;  // L1/L2/alpha handled by prep branch
    } else {
      if (i < B9) { src = s8; off = i - B8; hdst = O1H + off; }
      else { src = s9; off = i - B9; hdst = O2H + off; }
    }
    f16x8 h;
    if (isbf) {
      us8 raw = *reinterpret_cast<const us8*>((const unsigned short*)src + off);
#pragma unroll
      for (int j = 0; j < 8; ++j)
        h[j] = f2h(__uint_as_float(((u32)raw[j]) << 16));
    } else {
      const float4* fp = reinterpret_cast<const float4*>((const float*)src + off);
      float4 a = fp[0], b = fp[1];
      h[0] = f2h(a.x); h[1] = f2h(a.y); h[2] = f2h(a.z); h[3] = f2h(a.w);
      h[4] = f2h(b.x); h[5] = f2h(b.y); h[6] = f2h(b.z); h[7] = f2h(b.w);
    }
    *reinterpret_cast<f16x8*>(hb + hdst) = h;
    return;
  }

  // ---- prep branch: packs from RAW L1/L2/alpha (s5/s6/s7)
  int p = (blockIdx.x - CVT_BLOCKS) * 256 + threadIdx.x;
  if (p < 1024) {  // W1G01: dense g0/g1 planes [tile][lp<32][8]
    int tile = p >> 5, lp = p & 31;
    int rho = lp & 15, gg = lp >> 4;
    int k2 = tile >> 1, m = tile & 1;
    int u = k2 * 32 + 8 * (rho >> 2) + 4 * m + (rho & 3);
#pragma unroll
    for (int j = 0; j < 8; ++j) {
      int feat = 8 * gg + j;  // 0..15
      hb[W1G01 + p * 8 + j] = f2h(rdraw(s5, u * 32 + 2 * feat, isbf));
    }
  } else if (p < 2048) {  // L2PACK [k2][lane][8]
    int i2 = p - 1024;
    int k2 = i2 >> 6, l = i2 & 63;
    int head = l & 15, gg = l >> 4;
#pragma unroll
    for (int j = 0; j < 8; ++j)
      hb[L2PACK + i2 * 8 + j] = f2h(rdraw(s6, head * 512 + k2 * 32 + 8 * gg + j, isbf));
  } else if (p < 2560) {  // BETAP [tile][rho]
    int j = p - 2048;
    int tile = j >> 4, rho = j & 15;
    int k2 = tile >> 1, m = tile & 1;
    int u = k2 * 32 + 8 * (rho >> 2) + 4 * m + (rho & 3);
    float beta = 0.f;
#pragma unroll
    for (int h = 0; h < kH; ++h)
      beta += rdraw(s5, u * 32 + 2 * h + 1, isbf) * rdraw(s7, h, isbf);
    hb[BETAP + j] = f2h(beta);
  } else if (p < 2560 + 6144) {  // vt zero-pad: 2048 rows x 3 f16x8 stores
    int z = p - 2560;
    int row = z / 3, j = z % 3;  // cols 200+8j (byte off 400+16j: 16B-aligned)
    const f16x8 zz = {0, 0, 0, 0, 0, 0, 0, 0};
    *reinterpret_cast<f16x8*>(hb + VT1 + row * 224 + 200 + j * 8) = zz;
    *reinterpret_cast<f16x8*>(hb + VT2 + row * 224 + 200 + j * 8) = zz;
  }
}

// ---- QKV as MFMA GEMM, both dirs via z: out = x(1600x256) @ W^T(256x512) ---
__global__ __launch_bounds__(256) void qkv_gemm_kernel(_Float16* __restrict__ hb) {
  const int z = blockIdx.z;
  const _Float16* x16 = hb + (z ? X2H : X1H);
  const _Float16* w16 = hb + (z ? WKH : WQH);
  _Float16* oqk = hb + (z ? KH : QH);
  _Float16* vt = hb + (z ? VT2 : VT1);
  const float scale = z ? 1.0f : 0.25f;
  const int l = threadIdx.x & 63;
  const int w = threadIdx.x >> 6;
  const int m0 = blockIdx.y * 16;
  const int c0 = blockIdx.x * 64 + w * 16;
  const int arow = m0 + (l & 15);
  const int bcol = c0 + (l & 15);
  const int kb = (l >> 4) * 8;
  const f16x8* ap = reinterpret_cast<const f16x8*>(x16 + (size_t)arow * 256 + kb);
  const f16x8* bp = reinterpret_cast<const f16x8*>(w16 + (size_t)bcol * 256 + kb);
  f32x4 acc = {0.f, 0.f, 0.f, 0.f};
#pragma unroll
  for (int s = 0; s < 8; ++s)
    acc = __builtin_amdgcn_mfma_f32_16x16x32_f16(ap[s * 4], bp[s * 4], acc, 0, 0, 0);
#pragma unroll
  for (int t = 0; t < 4; ++t) {
    int rr = m0 + (l >> 4) * 4 + t;
    int cc = c0 + (l & 15);
    int b = rr / 200, r = rr - b * 200;
    if (cc < 256) {
      oqk[((b * 16 + (cc >> 4)) * 200 + r) * 16 + (cc & 15)] = f2h(scale * acc[t]);
    } else {
      int h = (cc - 256) >> 4, d = (cc - 256) & 15;
      vt[(size_t)((b * 16 + h) * 16 + d) * 224 + r] = f2h(acc[t]);
    }
  }
}

// ---- MFMA mixed kernel: 4 waves/block, W1 in block LDS, split accumulators -
__global__ __launch_bounds__(256) void mixed_mfma_kernel(_Float16* __restrict__ hb) {
  __shared__ _Float16 wlds[8192];             // [32 tiles][32 lanes][8]
  __shared__ _Float16 betalds[512];           // [32 tiles][16 rho]
  __shared__ _Float16 scores[4096];           // [r16][p16][f16], XOR-swizzled
  __shared__ _Float16 mixtile[16 * 16 * 24];  // [h][c][r pad 24]

  const int tid = threadIdx.x;
  const int l = tid & 63;
  const int wv = tid >> 6;
  const int p = l & 15;
  const int g = l >> 4;
  const int b = blockIdx.z;
  const int rt = blockIdx.y, ct = blockIdx.x;
  const int r0 = rt * 16, c0 = ct * 16;
  const f32x4 fzero = {0.f, 0.f, 0.f, 0.f};
  const f16x8 hzero = {0, 0, 0, 0, 0, 0, 0, 0};
  const _Float16* qh = hb + QH;
  const _Float16* kh = hb + KH;
  const _Float16* costh = hb + COSTH;

  // stage W1 planes + beta into LDS (block-shared)
  {
    const f16x8* src = reinterpret_cast<const f16x8*>(hb + W1G01);
    f16x8* dst = reinterpret_cast<f16x8*>(wlds);
#pragma unroll
    for (int i = 0; i < 4; ++i) dst[i * 256 + tid] = src[i * 256 + tid];
    reinterpret_cast<u32*>(betalds)[tid] =
        reinterpret_cast<const u32*>(hb + BETAP)[tid];
  }

  // L2 fragments in registers (64 VGPR, per-wave; indices ALL compile-time)
  f16x8 l2f[16];
  {
    const f16x8* lp2 = reinterpret_cast<const f16x8*>(hb + L2PACK) + l;
#pragma unroll
    for (int t = 0; t < 16; ++t) l2f[t] = lp2[t * 64];
  }

  // ---- QK phase: this wave computes its 4 heads (hc = wv)
  int qrow = r0 + p; if (qrow > 199) qrow = 199;
  int krow = c0 + p; if (krow > 199) krow = 199;
  {
    const int hc = wv;
    f32x4 acc[4];
#pragma unroll
    for (int i = 0; i < 4; ++i) {
      int h = hc * 4 + i;
      f16x8 qf = hzero, kf = hzero;
      if (g < 2) {
        qf = *reinterpret_cast<const f16x8*>(qh + ((b * 16 + h) * 200 + qrow) * 16 + 8 * g);
        kf = *reinterpret_cast<const f16x8*>(kh + ((b * 16 + h) * 200 + krow) * 16 + 8 * g);
      }
      acc[i] = __builtin_amdgcn_mfma_f32_16x16x32_f16(qf, kf, fzero, 0, 0, 0);
    }
#pragma unroll
    for (int pr = 0; pr < 2; ++pr) {
      int h = hc * 4 + pr * 2;
#pragma unroll
      for (int t = 0; t < 4; ++t) {
        u32 pk = pack2(acc[pr * 2][t], acc[pr * 2 + 1][t]);
        u32 a = (u32)((4 * g + t) * 512 + p * 32 + h * 2) ^ (((p >> 2) & 3) << 4);
        *reinterpret_cast<u32*>(reinterpret_cast<char*>(scores) + a) = pk;
      }
    }
  }
  __syncthreads();  // covers weight staging + scores

  // ---- main loop: rows r = wv*4 + {0..3}, 2 chains x 2 split accumulators.
  // k2 loop FULLY unrolled (rule #20: l2f[k2] runtime-indexed would spill).
  int ccol = c0 + p; if (ccol > 199) ccol = 199;
#pragma unroll
  for (int rr = 0; rr < 4; rr += 2) {
    const int rA = wv * 4 + rr, rB = rA + 1;
    u32 aA = (u32)(rA * 512 + p * 32 + (g & 1) * 16) ^ (((p >> 2) & 3) << 4);
    u32 aB = (u32)(rB * 512 + p * 32 + (g & 1) * 16) ^ (((p >> 2) & 3) << 4);
    f16x8 sfA = *reinterpret_cast<const f16x8*>(reinterpret_cast<char*>(scores) + aA);
    f16x8 sfB = *reinterpret_cast<const f16x8*>(reinterpret_cast<char*>(scores) + aB);
    int rrA = r0 + rA; if (rrA > 199) rrA = 199;
    int rrB = r0 + rB; if (rrB > 199) rrB = 199;
    _Float16 cvA = costh[(b * 200 + rrA) * 200 + ccol];
    _Float16 cvB = costh[(b * 200 + rrB) * 200 + ccol];
    f16x8 bfA, bfB;
    if (g < 2) { bfA = sfA; bfB = sfB; }
    else if (g == 2) {
      bfA = hzero; bfA[0] = cvA;
      bfB = hzero; bfB[0] = cvB;
    } else { bfA = hzero; bfB = hzero; }

    f32x4 mA0 = fzero, mA1 = fzero, mB0 = fzero, mB1 = fzero;
#pragma unroll
    for (int k2 = 0; k2 < 16; ++k2) {
      f16x8 w1a, w1b;
      if (l < 32) {
        w1a = *reinterpret_cast<const f16x8*>(&wlds[(2 * k2) * 256 + l * 8]);
        w1b = *reinterpret_cast<const f16x8*>(&wlds[(2 * k2 + 1) * 256 + l * 8]);
      } else if (g == 2) {
        w1a = hzero; w1a[0] = betalds[(2 * k2) * 16 + p];
        w1b = hzero; w1b[0] = betalds[(2 * k2 + 1) * 16 + p];
      } else { w1a = hzero; w1b = hzero; }

      f32x4 h0A = __builtin_amdgcn_mfma_f32_16x16x32_f16(w1a, bfA, fzero, 0, 0, 0);
      f32x4 h1A = __builtin_amdgcn_mfma_f32_16x16x32_f16(w1b, bfA, fzero, 0, 0, 0);
      f32x4 h0B = __builtin_amdgcn_mfma_f32_16x16x32_f16(w1a, bfB, fzero, 0, 0, 0);
      f32x4 h1B = __builtin_amdgcn_mfma_f32_16x16x32_f16(w1b, bfB, fzero, 0, 0, 0);
      // convert-then-relu: RTZ is monotone, so max(cvt(x),0) == cvt(max(x,0))
      i32x4 piA = {(int)pkrtz(h0A[0], h0A[1]), (int)pkrtz(h0A[2], h0A[3]),
                   (int)pkrtz(h1A[0], h1A[1]), (int)pkrtz(h1A[2], h1A[3])};
      i32x4 piB = {(int)pkrtz(h0B[0], h0B[1]), (int)pkrtz(h0B[2], h0B[3]),
                   (int)pkrtz(h1B[0], h1B[1]), (int)pkrtz(h1B[2], h1B[3])};
      f16x8 pa = __builtin_elementwise_max(__builtin_bit_cast(f16x8, piA), hzero);
      f16x8 pb = __builtin_elementwise_max(__builtin_bit_cast(f16x8, piB), hzero);
      // split accumulators: even k2 -> *0, odd k2 -> *1 (compile-time select)
      if (k2 & 1) {
        mA1 = __builtin_amdgcn_mfma_f32_16x16x32_f16(l2f[k2], pa, mA1, 0, 0, 0);
        mB1 = __builtin_amdgcn_mfma_f32_16x16x32_f16(l2f[k2], pb, mB1, 0, 0, 0);
      } else {
        mA0 = __builtin_amdgcn_mfma_f32_16x16x32_f16(l2f[k2], pa, mA0, 0, 0, 0);
        mB0 = __builtin_amdgcn_mfma_f32_16x16x32_f16(l2f[k2], pb, mB0, 0, 0, 0);
      }
    }
    f32x4 mA = mA0 + mA1, mB = mB0 + mB1;
#pragma unroll
    for (int t = 0; t < 4; ++t) {
      int h = 4 * g + t;
      mixtile[(h * 16 + p) * 24 + rA] = f2h(mA[t]);
      mixtile[(h * 16 + p) * 24 + rB] = f2h(mB[t]);
    }
  }
  __syncthreads();

  // ---- block-contiguous copy-out: one wave-instruction = 1KB consecutive ---
  // MIXA region [b][rt][ct] -> [h][n=r][m=c]; MIXB region [b][ct][rt] -> [h][m][n]
  {
    _Float16* regA = hb + MIXA + ((size_t)((b * 13 + rt) * 13 + ct)) * 4096;
    _Float16* regB = hb + MIXB + ((size_t)((b * 13 + ct) * 13 + rt)) * 4096;
#pragma unroll
    for (int k = 0; k < 2; ++k) {
      int e = k * 2048 + tid * 8;
      int h = e >> 8, rem = e & 255;
      int n = rem >> 4, m0 = rem & 15;  // m0 in {0,8}
      f16x8 va;
#pragma unroll
      for (int j = 0; j < 8; ++j) va[j] = mixtile[(h * 16 + m0 + j) * 24 + n];
      *reinterpret_cast<f16x8*>(regA + e) = va;
    }
#pragma unroll
    for (int k = 0; k < 2; ++k) {
      int e = k * 2048 + tid * 8;
      int h = e >> 8, rem = e & 255;
      int m = rem >> 4, n0 = rem & 15;  // n0 in {0,8}, 16B-aligned (pad 24)
      f16x8 vb = *reinterpret_cast<const f16x8*>(&mixtile[(h * 16 + m) * 24 + n0]);
      *reinterpret_cast<f16x8*>(regB + e) = vb;
    }
  }
}

// ---- fused softmax + P@vT: 4 waves/block (4 heads), barrier-free ------------
// grid (13 ntile, 4 hgroup, 16 = dir*8+b). logits read from tiled layouts.
__global__ __launch_bounds__(256) void fused_combine_kernel(
    _Float16* __restrict__ hb, const unsigned char* __restrict__ mask,
    const int* __restrict__ flags) {
  __shared__ _Float16 wt[4][16 * 256];  // per-wave 8KB chunk, XOR-swizzled rows
  const int z = blockIdx.z;
  const int dir = z >> 3, b = z & 7;
  const _Float16* lt = hb + (dir ? MIXB : MIXA);
  const int sn = dir ? 1 : 200, sm = dir ? 200 : 1;
  const _Float16* vt = hb + (dir ? VT1 : VT2);
  _Float16* wv = hb + (dir ? WV2 : WV1);
  const int wvid = threadIdx.x >> 6;
  const int l = threadIdx.x & 63;
  const int row = l & 15, grp = l >> 4;
  const int r0 = blockIdx.x * 16;
  const int h = blockIdx.y * 4 + wvid;
  const int bh = b * 16 + h;
  const int ms = flags[1];
  int n = r0 + row; if (n > 199) n = 199;  // clamp for mask only
  // tiled logits: [b][ntile][mtile][h][n_in=row][m_in]
  const _Float16* lgt = lt + (size_t)(b * 13 + blockIdx.x) * 53248 + h * 256 + row * 16;
  const unsigned char* mk = mask + ((size_t)b * 40000 + (size_t)n * sn) * ms;
  char* wtb = reinterpret_cast<char*>(wt[wvid]);

  float xv[7][8];
  float mx = kNEG;
#pragma unroll
  for (int i = 0; i < 7; ++i) {
    int c0 = grp * 8 + i * 32;
    if (c0 < 200) {  // c0 multiple of 8 -> c0+7 <= 199
      f16x8 lv = *reinterpret_cast<const f16x8*>(lgt + (c0 >> 4) * 4096 + (c0 & 15));
#pragma unroll
      for (int j = 0; j < 8; ++j) {
        bool mskd = mk[(size_t)(c0 + j) * sm * ms] != 0;
        float x = mskd ? kNEG : fast_tanh((float)lv[j]) * kCLIP;
        xv[i][j] = x;
        mx = fmaxf(mx, x);
      }
    } else {
#pragma unroll
      for (int j = 0; j < 8; ++j) xv[i][j] = kNEG;
    }
  }
  mx = fmaxf(mx, __shfl_xor(mx, 16));
  mx = fmaxf(mx, __shfl_xor(mx, 32));
  float se = 0.f;
#pragma unroll
  for (int i = 0; i < 7; ++i)
#pragma unroll
    for (int j = 0; j < 8; ++j) {
      float e = __expf(xv[i][j] - mx);
      xv[i][j] = e;
      se += e;
    }
  se += __shfl_xor(se, 16);
  se += __shfl_xor(se, 32);
  float inv = (mx <= -1e8f) ? 0.f : 1.f / se;  // all-masked row -> zero weights
#pragma unroll
  for (int i = 0; i < 7; ++i) {
    int c0 = grp * 8 + i * 32;
    f16x8 pv;
#pragma unroll
    for (int j = 0; j < 8; ++j) pv[j] = f2h(xv[i][j] * inv);
    u32 a = (u32)(row * 512 + c0 * 2) ^ (u32)((row & 7) << 4);
    *reinterpret_cast<f16x8*>(wtb + a) = pv;
  }
  // no barrier: wt chunk is written and read by this wave only (lgkmcnt order)

  f32x4 acc = {0.f, 0.f, 0.f, 0.f};
#pragma unroll
  for (int k2 = 0; k2 < 7; ++k2) {
    int kb = k2 * 32 + grp * 8;
    u32 a = (u32)(row * 512 + kb * 2) ^ (u32)((row & 7) << 4);
    f16x8 af = *reinterpret_cast<const f16x8*>(wtb + a);
    f16x8 bf = *reinterpret_cast<const f16x8*>(vt + (size_t)(bh * 16 + row) * 224 + kb);
    acc = __builtin_amdgcn_mfma_f32_16x16x32_f16(af, bf, acc, 0, 0, 0);
  }
#pragma unroll
  for (int t = 0; t < 4; ++t) {
    int r = r0 + grp * 4 + t;
    if (r < 200)
      wv[((size_t)b * 200 + r) * 256 + h * 16 + row] = f2h(acc[t]);
  }
}

// ---- out = wv(1600x256) @ Wout^T(256x256), both dirs via z ------------------
__global__ __launch_bounds__(256) void out_gemm_kernel(
    const _Float16* __restrict__ hb, void* __restrict__ out,
    const int* __restrict__ flags) {
  const int z = blockIdx.z;
  const _Float16* wvh = hb + (z ? WV2 : WV1);
  const _Float16* wout = hb + (z ? O2H : O1H);
  const int outOff = z ? 409600 : 0;
  const int l = threadIdx.x & 63;
  const int w = threadIdx.x >> 6;
  const int m0 = blockIdx.y * 16;
  const int c0 = blockIdx.x * 64 + w * 16;
  const int arow = m0 + (l & 15);
  const int bcol = c0 + (l & 15);
  const int kb = (l >> 4) * 8;
  const f16x8* ap = reinterpret_cast<const f16x8*>(wvh + (size_t)arow * 256 + kb);
  const f16x8* bp = reinterpret_cast<const f16x8*>(wout + (size_t)bcol * 256 + kb);
  f32x4 acc = {0.f, 0.f, 0.f, 0.f};
#pragma unroll
  for (int s = 0; s < 8; ++s)
    acc = __builtin_amdgcn_mfma_f32_16x16x32_f16(ap[s * 4], bp[s * 4], acc, 0, 0, 0);
  int isbf = flags[0];
#pragma unroll
  for (int t = 0; t < 4; ++t) {
    size_t oidx = (size_t)outOff + (size_t)(m0 + (l >> 4) * 4 + t) * 256 + c0 + (l & 15);
    if (isbf) ((__hip_bfloat16*)out)[oidx] = __float2bfloat16(acc[t]);
    else ((float*)out)[oidx] = acc[t];
  }
}

}  // namespace

extern "C" void kernel_launch(void* const* d_in, const int* in_sizes, int n_in,
                              void* d_out, int out_size, void* d_ws, size_t ws_size,
                              hipStream_t stream) {
  if (ws_size < WS_NEED) return;  // output stays zero -> loud failure
  const unsigned char* mask = (const unsigned char*)d_in[2];

  float* ws = (float*)d_ws;
  _Float16* hb = (_Float16*)(ws + F32_END);
  int* flags = (int*)(ws + FLAGS);

  cvtprep_kernel<<<dim3(CVT_BLOCKS + PREP_BLOCKS), 256, 0, stream>>>(
      d_in[0], d_in[1], d_in[3], d_in[4], d_in[5], d_in[6], d_in[7], d_in[8],
      d_in[9], d_in[10], mask, hb, flags);
  qkv_gemm_kernel<<<dim3(8, 100, 2), 256, 0, stream>>>(hb);
  mixed_mfma_kernel<<<dim3(13, 13, kB), 256, 0, stream>>>(hb);
  fused_combine_kernel<<<dim3(13, 4, 16), 256, 0, stream>>>(hb, mask, flags);
  out_gemm_kernel<<<dim3(4, 100, 2), 256, 0, stream>>>(hb, d_out, flags);
}

// Round 17
// 77.209 us; speedup vs baseline: 1.1698x; 1.1698x over previous
//
#include <hip/hip_runtime.h>
#include <hip/hip_bf16.h>
#include <math.h>

// EfficientMixedScoreMultiHeadAttentionLayer — round 17 (= r16 + dense masks).
// r16 post-mortem: both changes neutral (90.3 vs 89.9). Remaining named
// inefficiency: fused_combine's mask access — dir2 = 13M stride-200 byte
// gathers, dir1 = 8 byte-loads per 8 cols + ms-multiply. Fix: cvtprep builds
// dense u8 planes mask1[b][n][m] and maskT[b][n][m]=mask[b][m][n] once;
// combine reads one aligned u64 per 8 columns either direction.
// B=8, R=C=200, E=256, H=16, D=16, MS_HID=32, SDIMS=2.

namespace {
constexpr int kB = 8, kH = 16;
constexpr float kNEG = -1e9f;
constexpr float kCLIP = 10.f;

typedef _Float16 f16x8 __attribute__((ext_vector_type(8)));
typedef float f32x4 __attribute__((ext_vector_type(4)));
typedef int i32x4 __attribute__((ext_vector_type(4)));
typedef unsigned short us8 __attribute__((ext_vector_type(8)));
typedef unsigned int u32;
typedef unsigned long long u64;

// ---- input stream region boundaries (element index over concatenated inputs)
constexpr int B1 = 409600;    // x2
constexpr int B2 = 819200;    // cost
constexpr int B3 = 1139200;   // Wqv1
constexpr int B4 = 1270272;   // Wkv2
constexpr int B5 = 1401344;   // L1   (handled by prep branch)
constexpr int B8 = 1425936;   // o1w
constexpr int B9 = 1491472;   // o2w
constexpr int CVT_TOTAL = 1557008;
constexpr int CVT_BLOCKS = 761;   // ceil(CVT_TOTAL/8/256)
// prep work items: 1024 w1g01 + 1024 l2pack + 512 betap + 6144 vtpad + 40000 mask
constexpr int PREP_ITEMS = 48704;
constexpr int PREP_BLOCKS = 191;  // ceil(48704/256)

// ---- ws: flags then f16 heap
constexpr int FLAGS = 0;      // 16 ints
constexpr int F32_END = 16;
// f16 element offsets from hb base
constexpr int QH = 0;
constexpr int KH = 409600;
constexpr int W1G01 = 819200;         // 32 tiles x 32 lanes x 8 (dense g0/g1)
constexpr int BETAP = 827392;         // 32 tiles x 16
constexpr int L2PACK = 835584;        // 16 steps x 64 lanes x 8
constexpr int MIXA = 843776;          // 8b x 13 x 13 x 16h x 256 = 5,537,792
constexpr int MIXB = 6381568;         // 5,537,792
constexpr int X1H = 11919360;         // 409600
constexpr int X2H = 12328960;         // 409600
constexpr int WQH = 12738560;         // 131072
constexpr int WKH = 12869632;         // 131072
constexpr int VT1 = 13000704;         // 2048 rows x 224
constexpr int VT2 = 13459456;         // 2048 rows x 224
constexpr int WV1 = 13918208;         // 409600  [b][r][256]
constexpr int WV2 = 14327808;         // 409600  [b][c][256]
constexpr int O1H = 14737408;         // 65536
constexpr int O2H = 14802944;         // 65536
constexpr int COSTH = 14868480;       // 320000
constexpr int MASK1H = 15188480;      // 160000 f16 = 320000 u8: mask1[b][n][m]
constexpr int MASKTH = 15348480;      // 160000 f16 = 320000 u8: maskT[b][n][m]
constexpr size_t F16_END = 15508480;
constexpr size_t WS_NEED = (size_t)F32_END * 4 + F16_END * 2;  // ~31.0 MB

__device__ inline _Float16 f2h(float v) { return (_Float16)v; }
__device__ inline u32 pack2(float lo, float hi) {
  return (u32)__builtin_bit_cast(unsigned short, (_Float16)lo) |
         ((u32)__builtin_bit_cast(unsigned short, (_Float16)hi) << 16);
}
__device__ inline u32 pkrtz(float lo, float hi) {
  return __builtin_bit_cast(u32, __builtin_amdgcn_cvt_pkrtz(lo, hi));
}
__device__ inline float fast_tanh(float x) {
  float t = __expf(2.f * x);
  return (t - 1.f) * __builtin_amdgcn_rcpf(t + 1.f);
}
__device__ inline float rdraw(const void* s, int idx, int isbf) {
  return isbf ? __uint_as_float(((u32)((const unsigned short*)s)[idx]) << 16)
              : ((const float*)s)[idx];
}

// ---- cvt (x8 vectorized) + detect + weight pack + vt pad + mask planes -----
__global__ __launch_bounds__(256) void cvtprep_kernel(
    const void* s0, const void* s1, const void* s2, const void* s3,
    const void* s4, const void* s5, const void* s6, const void* s7,
    const void* s8, const void* s9, const unsigned char* __restrict__ mb,
    _Float16* __restrict__ hb, int* __restrict__ flags) {
  const int lane = threadIdx.x & 63;
  int bad = 0;
  const unsigned short* xp = (const unsigned short*)s0;
#pragma unroll
  for (int j = 0; j < 4; ++j) {
    float f = __uint_as_float(((u32)xp[lane * 4 + j]) << 16);
    if (!(fabsf(f) <= 1000.f)) bad = 1;  // catches NaN/inf too
  }
  const int isbf = __ballot(bad) ? 0 : 1;
  // mask element-size probe (needed by the mask-plane branch in every block)
  int nz = 0;
  for (int i = lane; i < 512; i += 64)
    if ((i & 3) && mb[i]) nz = 1;
  const int msz = __ballot(nz) ? 1 : 4;
  if (blockIdx.x == 0 && threadIdx.x == 0) { flags[0] = isbf; flags[1] = msz; }

  if (blockIdx.x < CVT_BLOCKS) {
    int i = (blockIdx.x * 256 + threadIdx.x) * 8;
    if (i >= CVT_TOTAL) return;
    const void* src;
    int off, hdst;
    if (i < B2) {
      if (i < B1) { src = s0; off = i; hdst = X1H + off; }
      else { src = s1; off = i - B1; hdst = X2H + off; }
    } else if (i < B4) {
      if (i < B3) { src = s2; off = i - B2; hdst = COSTH + off; }
      else { src = s3; off = i - B3; hdst = WQH + off; }
    } else if (i < B5) {
      src = s4; off = i - B4; hdst = WKH + off;
    } else if (i < B8) {
      return;  // L1/L2/alpha handled by prep branch
    } else {
      if (i < B9) { src = s8; off = i - B8; hdst = O1H + off; }
      else { src = s9; off = i - B9; hdst = O2H + off; }
    }
    f16x8 h;
    if (isbf) {
      us8 raw = *reinterpret_cast<const us8*>((const unsigned short*)src + off);
#pragma unroll
      for (int j = 0; j < 8; ++j)
        h[j] = f2h(__uint_as_float(((u32)raw[j]) << 16));
    } else {
      const float4* fp = reinterpret_cast<const float4*>((const float*)src + off);
      float4 a = fp[0], b = fp[1];
      h[0] = f2h(a.x); h[1] = f2h(a.y); h[2] = f2h(a.z); h[3] = f2h(a.w);
      h[4] = f2h(b.x); h[5] = f2h(b.y); h[6] = f2h(b.z); h[7] = f2h(b.w);
    }
    *reinterpret_cast<f16x8*>(hb + hdst) = h;
    return;
  }

  // ---- prep branch: packs from RAW L1/L2/alpha (s5/s6/s7) + mask planes
  int p = (blockIdx.x - CVT_BLOCKS) * 256 + threadIdx.x;
  if (p < 1024) {  // W1G01: dense g0/g1 planes [tile][lp<32][8]
    int tile = p >> 5, lp = p & 31;
    int rho = lp & 15, gg = lp >> 4;
    int k2 = tile >> 1, m = tile & 1;
    int u = k2 * 32 + 8 * (rho >> 2) + 4 * m + (rho & 3);
#pragma unroll
    for (int j = 0; j < 8; ++j) {
      int feat = 8 * gg + j;  // 0..15
      hb[W1G01 + p * 8 + j] = f2h(rdraw(s5, u * 32 + 2 * feat, isbf));
    }
  } else if (p < 2048) {  // L2PACK [k2][lane][8]
    int i2 = p - 1024;
    int k2 = i2 >> 6, l = i2 & 63;
    int head = l & 15, gg = l >> 4;
#pragma unroll
    for (int j = 0; j < 8; ++j)
      hb[L2PACK + i2 * 8 + j] = f2h(rdraw(s6, head * 512 + k2 * 32 + 8 * gg + j, isbf));
  } else if (p < 2560) {  // BETAP [tile][rho]
    int j = p - 2048;
    int tile = j >> 4, rho = j & 15;
    int k2 = tile >> 1, m = tile & 1;
    int u = k2 * 32 + 8 * (rho >> 2) + 4 * m + (rho & 3);
    float beta = 0.f;
#pragma unroll
    for (int h = 0; h < kH; ++h)
      beta += rdraw(s5, u * 32 + 2 * h + 1, isbf) * rdraw(s7, h, isbf);
    hb[BETAP + j] = f2h(beta);
  } else if (p < 8704) {  // vt zero-pad: 2048 rows x 3 f16x8 stores
    int z = p - 2560;
    int row = z / 3, j = z % 3;  // cols 200+8j (byte off 400+16j: 16B-aligned)
    const f16x8 zz = {0, 0, 0, 0, 0, 0, 0, 0};
    *reinterpret_cast<f16x8*>(hb + VT1 + row * 224 + 200 + j * 8) = zz;
    *reinterpret_cast<f16x8*>(hb + VT2 + row * 224 + 200 + j * 8) = zz;
  } else if (p < PREP_ITEMS) {  // mask planes: mask1[b][n][m], maskT[b][n][m]
    int t = p - 8704;           // 40000 = 8b x 25 ngrp... b*5000 + n*25 + mgrp
    int b = t / 5000, rem = t % 5000;
    int n = rem / 25, m0 = (rem % 25) * 8;
    u64 w1 = 0, wt = 0;
    if (msz == 1) {
      w1 = *reinterpret_cast<const u64*>(mb + (size_t)b * 40000 + n * 200 + m0);
#pragma unroll
      for (int j = 0; j < 8; ++j)
        wt |= (u64)(mb[(size_t)b * 40000 + (m0 + j) * 200 + n] ? 1 : 0) << (8 * j);
    } else {
      const int* mi = (const int*)mb;
#pragma unroll
      for (int j = 0; j < 8; ++j) {
        w1 |= (u64)(mi[(size_t)b * 40000 + n * 200 + m0 + j] ? 1 : 0) << (8 * j);
        wt |= (u64)(mi[(size_t)b * 40000 + (m0 + j) * 200 + n] ? 1 : 0) << (8 * j);
      }
    }
    *reinterpret_cast<u64*>((unsigned char*)(hb + MASK1H) + (size_t)b * 40000 + n * 200 + m0) = w1;
    *reinterpret_cast<u64*>((unsigned char*)(hb + MASKTH) + (size_t)b * 40000 + n * 200 + m0) = wt;
  }
}

// ---- QKV as MFMA GEMM, both dirs via z: out = x(1600x256) @ W^T(256x512) ---
__global__ __launch_bounds__(256) void qkv_gemm_kernel(_Float16* __restrict__ hb) {
  const int z = blockIdx.z;
  const _Float16* x16 = hb + (z ? X2H : X1H);
  const _Float16* w16 = hb + (z ? WKH : WQH);
  _Float16* oqk = hb + (z ? KH : QH);
  _Float16* vt = hb + (z ? VT2 : VT1);
  const float scale = z ? 1.0f : 0.25f;
  const int l = threadIdx.x & 63;
  const int w = threadIdx.x >> 6;
  const int m0 = blockIdx.y * 16;
  const int c0 = blockIdx.x * 64 + w * 16;
  const int arow = m0 + (l & 15);
  const int bcol = c0 + (l & 15);
  const int kb = (l >> 4) * 8;
  const f16x8* ap = reinterpret_cast<const f16x8*>(x16 + (size_t)arow * 256 + kb);
  const f16x8* bp = reinterpret_cast<const f16x8*>(w16 + (size_t)bcol * 256 + kb);
  f32x4 acc = {0.f, 0.f, 0.f, 0.f};
#pragma unroll
  for (int s = 0; s < 8; ++s)
    acc = __builtin_amdgcn_mfma_f32_16x16x32_f16(ap[s * 4], bp[s * 4], acc, 0, 0, 0);
#pragma unroll
  for (int t = 0; t < 4; ++t) {
    int rr = m0 + (l >> 4) * 4 + t;
    int cc = c0 + (l & 15);
    int b = rr / 200, r = rr - b * 200;
    if (cc < 256) {
      oqk[((b * 16 + (cc >> 4)) * 200 + r) * 16 + (cc & 15)] = f2h(scale * acc[t]);
    } else {
      int h = (cc - 256) >> 4, d = (cc - 256) & 15;
      vt[(size_t)((b * 16 + h) * 16 + d) * 224 + r] = f2h(acc[t]);
    }
  }
}

// ---- MFMA mixed kernel: 4 waves/block, W1 in block LDS, split accumulators -
__global__ __launch_bounds__(256) void mixed_mfma_kernel(_Float16* __restrict__ hb) {
  __shared__ _Float16 wlds[8192];             // [32 tiles][32 lanes][8]
  __shared__ _Float16 betalds[512];           // [32 tiles][16 rho]
  __shared__ _Float16 scores[4096];           // [r16][p16][f16], XOR-swizzled
  __shared__ _Float16 mixtile[16 * 16 * 24];  // [h][c][r pad 24]

  const int tid = threadIdx.x;
  const int l = tid & 63;
  const int wv = tid >> 6;
  const int p = l & 15;
  const int g = l >> 4;
  const int b = blockIdx.z;
  const int rt = blockIdx.y, ct = blockIdx.x;
  const int r0 = rt * 16, c0 = ct * 16;
  const f32x4 fzero = {0.f, 0.f, 0.f, 0.f};
  const f16x8 hzero = {0, 0, 0, 0, 0, 0, 0, 0};
  const _Float16* qh = hb + QH;
  const _Float16* kh = hb + KH;
  const _Float16* costh = hb + COSTH;

  // stage W1 planes + beta into LDS (block-shared)
  {
    const f16x8* src = reinterpret_cast<const f16x8*>(hb + W1G01);
    f16x8* dst = reinterpret_cast<f16x8*>(wlds);
#pragma unroll
    for (int i = 0; i < 4; ++i) dst[i * 256 + tid] = src[i * 256 + tid];
    reinterpret_cast<u32*>(betalds)[tid] =
        reinterpret_cast<const u32*>(hb + BETAP)[tid];
  }

  // L2 fragments in registers (64 VGPR, per-wave; indices ALL compile-time)
  f16x8 l2f[16];
  {
    const f16x8* lp2 = reinterpret_cast<const f16x8*>(hb + L2PACK) + l;
#pragma unroll
    for (int t = 0; t < 16; ++t) l2f[t] = lp2[t * 64];
  }

  // ---- QK phase: this wave computes its 4 heads (hc = wv)
  int qrow = r0 + p; if (qrow > 199) qrow = 199;
  int krow = c0 + p; if (krow > 199) krow = 199;
  {
    const int hc = wv;
    f32x4 acc[4];
#pragma unroll
    for (int i = 0; i < 4; ++i) {
      int h = hc * 4 + i;
      f16x8 qf = hzero, kf = hzero;
      if (g < 2) {
        qf = *reinterpret_cast<const f16x8*>(qh + ((b * 16 + h) * 200 + qrow) * 16 + 8 * g);
        kf = *reinterpret_cast<const f16x8*>(kh + ((b * 16 + h) * 200 + krow) * 16 + 8 * g);
      }
      acc[i] = __builtin_amdgcn_mfma_f32_16x16x32_f16(qf, kf, fzero, 0, 0, 0);
    }
#pragma unroll
    for (int pr = 0; pr < 2; ++pr) {
      int h = hc * 4 + pr * 2;
#pragma unroll
      for (int t = 0; t < 4; ++t) {
        u32 pk = pack2(acc[pr * 2][t], acc[pr * 2 + 1][t]);
        u32 a = (u32)((4 * g + t) * 512 + p * 32 + h * 2) ^ (((p >> 2) & 3) << 4);
        *reinterpret_cast<u32*>(reinterpret_cast<char*>(scores) + a) = pk;
      }
    }
  }
  __syncthreads();  // covers weight staging + scores

  // ---- main loop: rows r = wv*4 + {0..3}, 2 chains x 2 split accumulators.
  // k2 loop FULLY unrolled (rule #20: l2f[k2] runtime-indexed would spill).
  int ccol = c0 + p; if (ccol > 199) ccol = 199;
#pragma unroll
  for (int rr = 0; rr < 4; rr += 2) {
    const int rA = wv * 4 + rr, rB = rA + 1;
    u32 aA = (u32)(rA * 512 + p * 32 + (g & 1) * 16) ^ (((p >> 2) & 3) << 4);
    u32 aB = (u32)(rB * 512 + p * 32 + (g & 1) * 16) ^ (((p >> 2) & 3) << 4);
    f16x8 sfA = *reinterpret_cast<const f16x8*>(reinterpret_cast<char*>(scores) + aA);
    f16x8 sfB = *reinterpret_cast<const f16x8*>(reinterpret_cast<char*>(scores) + aB);
    int rrA = r0 + rA; if (rrA > 199) rrA = 199;
    int rrB = r0 + rB; if (rrB > 199) rrB = 199;
    _Float16 cvA = costh[(b * 200 + rrA) * 200 + ccol];
    _Float16 cvB = costh[(b * 200 + rrB) * 200 + ccol];
    f16x8 bfA, bfB;
    if (g < 2) { bfA = sfA; bfB = sfB; }
    else if (g == 2) {
      bfA = hzero; bfA[0] = cvA;
      bfB = hzero; bfB[0] = cvB;
    } else { bfA = hzero; bfB = hzero; }

    f32x4 mA0 = fzero, mA1 = fzero, mB0 = fzero, mB1 = fzero;
#pragma unroll
    for (int k2 = 0; k2 < 16; ++k2) {
      f16x8 w1a, w1b;
      if (l < 32) {
        w1a = *reinterpret_cast<const f16x8*>(&wlds[(2 * k2) * 256 + l * 8]);
        w1b = *reinterpret_cast<const f16x8*>(&wlds[(2 * k2 + 1) * 256 + l * 8]);
      } else if (g == 2) {
        w1a = hzero; w1a[0] = betalds[(2 * k2) * 16 + p];
        w1b = hzero; w1b[0] = betalds[(2 * k2 + 1) * 16 + p];
      } else { w1a = hzero; w1b = hzero; }

      f32x4 h0A = __builtin_amdgcn_mfma_f32_16x16x32_f16(w1a, bfA, fzero, 0, 0, 0);
      f32x4 h1A = __builtin_amdgcn_mfma_f32_16x16x32_f16(w1b, bfA, fzero, 0, 0, 0);
      f32x4 h0B = __builtin_amdgcn_mfma_f32_16x16x32_f16(w1a, bfB, fzero, 0, 0, 0);
      f32x4 h1B = __builtin_amdgcn_mfma_f32_16x16x32_f16(w1b, bfB, fzero, 0, 0, 0);
      // convert-then-relu: RTZ is monotone, so max(cvt(x),0) == cvt(max(x,0))
      i32x4 piA = {(int)pkrtz(h0A[0], h0A[1]), (int)pkrtz(h0A[2], h0A[3]),
                   (int)pkrtz(h1A[0], h1A[1]), (int)pkrtz(h1A[2], h1A[3])};
      i32x4 piB = {(int)pkrtz(h0B[0], h0B[1]), (int)pkrtz(h0B[2], h0B[3]),
                   (int)pkrtz(h1B[0], h1B[1]), (int)pkrtz(h1B[2], h1B[3])};
      f16x8 pa = __builtin_elementwise_max(__builtin_bit_cast(f16x8, piA), hzero);
      f16x8 pb = __builtin_elementwise_max(__builtin_bit_cast(f16x8, piB), hzero);
      if (k2 & 1) {
        mA1 = __builtin_amdgcn_mfma_f32_16x16x32_f16(l2f[k2], pa, mA1, 0, 0, 0);
        mB1 = __builtin_amdgcn_mfma_f32_16x16x32_f16(l2f[k2], pb, mB1, 0, 0, 0);
      } else {
        mA0 = __builtin_amdgcn_mfma_f32_16x16x32_f16(l2f[k2], pa, mA0, 0, 0, 0);
        mB0 = __builtin_amdgcn_mfma_f32_16x16x32_f16(l2f[k2], pb, mB0, 0, 0, 0);
      }
    }
    f32x4 mA = mA0 + mA1, mB = mB0 + mB1;
#pragma unroll
    for (int t = 0; t < 4; ++t) {
      int h = 4 * g + t;
      mixtile[(h * 16 + p) * 24 + rA] = f2h(mA[t]);
      mixtile[(h * 16 + p) * 24 + rB] = f2h(mB[t]);
    }
  }
  __syncthreads();

  // ---- block-contiguous copy-out: one wave-instruction = 1KB consecutive ---
  // MIXA region [b][rt][ct] -> [h][n=r][m=c]; MIXB region [b][ct][rt] -> [h][m][n]
  {
    _Float16* regA = hb + MIXA + ((size_t)((b * 13 + rt) * 13 + ct)) * 4096;
    _Float16* regB = hb + MIXB + ((size_t)((b * 13 + ct) * 13 + rt)) * 4096;
#pragma unroll
    for (int k = 0; k < 2; ++k) {
      int e = k * 2048 + tid * 8;
      int h = e >> 8, rem = e & 255;
      int n = rem >> 4, m0 = rem & 15;  // m0 in {0,8}
      f16x8 va;
#pragma unroll
      for (int j = 0; j < 8; ++j) va[j] = mixtile[(h * 16 + m0 + j) * 24 + n];
      *reinterpret_cast<f16x8*>(regA + e) = va;
    }
#pragma unroll
    for (int k = 0; k < 2; ++k) {
      int e = k * 2048 + tid * 8;
      int h = e >> 8, rem = e & 255;
      int m = rem >> 4, n0 = rem & 15;  // n0 in {0,8}, 16B-aligned (pad 24)
      f16x8 vb = *reinterpret_cast<const f16x8*>(&mixtile[(h * 16 + m) * 24 + n0]);
      *reinterpret_cast<f16x8*>(regB + e) = vb;
    }
  }
}

// ---- fused softmax + P@vT: 4 waves/block (4 heads), barrier-free ------------
// grid (13 ntile, 4 hgroup, 16 = dir*8+b). dense u8 mask planes, u64 reads.
__global__ __launch_bounds__(256) void fused_combine_kernel(
    _Float16* __restrict__ hb, const int* __restrict__ flags) {
  __shared__ _Float16 wt[4][16 * 256];  // per-wave 8KB chunk, XOR-swizzled rows
  const int z = blockIdx.z;
  const int dir = z >> 3, b = z & 7;
  const _Float16* lt = hb + (dir ? MIXB : MIXA);
  const _Float16* vt = hb + (dir ? VT1 : VT2);
  _Float16* wv = hb + (dir ? WV2 : WV1);
  const unsigned char* mplane =
      (const unsigned char*)(hb + (dir ? MASKTH : MASK1H));
  const int wvid = threadIdx.x >> 6;
  const int l = threadIdx.x & 63;
  const int row = l & 15, grp = l >> 4;
  const int r0 = blockIdx.x * 16;
  const int h = blockIdx.y * 4 + wvid;
  const int bh = b * 16 + h;
  int n = r0 + row; if (n > 199) n = 199;  // clamp for mask only
  // tiled logits: [b][ntile][mtile][h][n_in=row][m_in]
  const _Float16* lgt = lt + (size_t)(b * 13 + blockIdx.x) * 53248 + h * 256 + row * 16;
  const unsigned char* mk = mplane + (size_t)b * 40000 + n * 200;
  char* wtb = reinterpret_cast<char*>(wt[wvid]);

  float xv[7][8];
  float mx = kNEG;
#pragma unroll
  for (int i = 0; i < 7; ++i) {
    int c0 = grp * 8 + i * 32;
    if (c0 < 200) {  // c0 multiple of 8 -> c0+7 <= 199
      f16x8 lv = *reinterpret_cast<const f16x8*>(lgt + (c0 >> 4) * 4096 + (c0 & 15));
      u64 mv = *reinterpret_cast<const u64*>(mk + c0);
#pragma unroll
      for (int j = 0; j < 8; ++j) {
        bool mskd = ((mv >> (8 * j)) & 0xffull) != 0;
        float x = mskd ? kNEG : fast_tanh((float)lv[j]) * kCLIP;
        xv[i][j] = x;
        mx = fmaxf(mx, x);
      }
    } else {
#pragma unroll
      for (int j = 0; j < 8; ++j) xv[i][j] = kNEG;
    }
  }
  mx = fmaxf(mx, __shfl_xor(mx, 16));
  mx = fmaxf(mx, __shfl_xor(mx, 32));
  float se = 0.f;
#pragma unroll
  for (int i = 0; i < 7; ++i)
#pragma unroll
    for (int j = 0; j < 8; ++j) {
      float e = __expf(xv[i][j] - mx);
      xv[i][j] = e;
      se += e;
    }
  se += __shfl_xor(se, 16);
  se += __shfl_xor(se, 32);
  float inv = (mx <= -1e8f) ? 0.f : 1.f / se;  // all-masked row -> zero weights
#pragma unroll
  for (int i = 0; i < 7; ++i) {
    int c0 = grp * 8 + i * 32;
    f16x8 pv;
#pragma unroll
    for (int j = 0; j < 8; ++j) pv[j] = f2h(xv[i][j] * inv);
    u32 a = (u32)(row * 512 + c0 * 2) ^ (u32)((row & 7) << 4);
    *reinterpret_cast<f16x8*>(wtb + a) = pv;
  }
  // no barrier: wt chunk is written and read by this wave only (lgkmcnt order)

  f32x4 acc = {0.f, 0.f, 0.f, 0.f};
#pragma unroll
  for (int k2 = 0; k2 < 7; ++k2) {
    int kb = k2 * 32 + grp * 8;
    u32 a = (u32)(row * 512 + kb * 2) ^ (u32)((row & 7) << 4);
    f16x8 af = *reinterpret_cast<const f16x8*>(wtb + a);
    f16x8 bf = *reinterpret_cast<const f16x8*>(vt + (size_t)(bh * 16 + row) * 224 + kb);
    acc = __builtin_amdgcn_mfma_f32_16x16x32_f16(af, bf, acc, 0, 0, 0);
  }
#pragma unroll
  for (int t = 0; t < 4; ++t) {
    int r = r0 + grp * 4 + t;
    if (r < 200)
      wv[((size_t)b * 200 + r) * 256 + h * 16 + row] = f2h(acc[t]);
  }
}

// ---- out = wv(1600x256) @ Wout^T(256x256), both dirs via z ------------------
__global__ __launch_bounds__(256) void out_gemm_kernel(
    const _Float16* __restrict__ hb, void* __restrict__ out,
    const int* __restrict__ flags) {
  const int z = blockIdx.z;
  const _Float16* wvh = hb + (z ? WV2 : WV1);
  const _Float16* wout = hb + (z ? O2H : O1H);
  const int outOff = z ? 409600 : 0;
  const int l = threadIdx.x & 63;
  const int w = threadIdx.x >> 6;
  const int m0 = blockIdx.y * 16;
  const int c0 = blockIdx.x * 64 + w * 16;
  const int arow = m0 + (l & 15);
  const int bcol = c0 + (l & 15);
  const int kb = (l >> 4) * 8;
  const f16x8* ap = reinterpret_cast<const f16x8*>(wvh + (size_t)arow * 256 + kb);
  const f16x8* bp = reinterpret_cast<const f16x8*>(wout + (size_t)bcol * 256 + kb);
  f32x4 acc = {0.f, 0.f, 0.f, 0.f};
#pragma unroll
  for (int s = 0; s < 8; ++s)
    acc = __builtin_amdgcn_mfma_f32_16x16x32_f16(ap[s * 4], bp[s * 4], acc, 0, 0, 0);
  int isbf = flags[0];
#pragma unroll
  for (int t = 0; t < 4; ++t) {
    size_t oidx = (size_t)outOff + (size_t)(m0 + (l >> 4) * 4 + t) * 256 + c0 + (l & 15);
    if (isbf) ((__hip_bfloat16*)out)[oidx] = __float2bfloat16(acc[t]);
    else ((float*)out)[oidx] = acc[t];
  }
}

}  // namespace

extern "C" void kernel_launch(void* const* d_in, const int* in_sizes, int n_in,
                              void* d_out, int out_size, void* d_ws, size_t ws_size,
                              hipStream_t stream) {
  if (ws_size < WS_NEED) return;  // output stays zero -> loud failure
  const unsigned char* mask = (const unsigned char*)d_in[2];

  float* ws = (float*)d_ws;
  _Float16* hb = (_Float16*)(ws + F32_END);
  int* flags = (int*)(ws + FLAGS);

  cvtprep_kernel<<<dim3(CVT_BLOCKS + PREP_BLOCKS), 256, 0, stream>>>(
      d_in[0], d_in[1], d_in[3], d_in[4], d_in[5], d_in[6], d_in[7], d_in[8],
      d_in[9], d_in[10], mask, hb, flags);
  qkv_gemm_kernel<<<dim3(8, 100, 2), 256, 0, stream>>>(hb);
  mixed_mfma_kernel<<<dim3(13, 13, kB), 256, 0, stream>>>(hb);
  fused_combine_kernel<<<dim3(13, 4, 16), 256, 0, stream>>>(hb, flags);
  out_gemm_kernel<<<dim3(4, 100, 2), 256, 0, stream>>>(hb, d_out, flags);
}

// Round 18
// 75.587 us; speedup vs baseline: 1.1949x; 1.0215x over previous
//
#include <hip/hip_runtime.h>
#include <hip/hip_bf16.h>
#include <math.h>

// EfficientMixedScoreMultiHeadAttentionLayer — round 18 (= r17 + shared tanh).
// (1) tanh(m)*10 moved into mixed's epilogue (computed once for both combine
//     directions: 10.8M -> 5.4M tanh; f16 post-tanh storage is also more
//     precise). (2) combine softmax uses constant shift 10 (logits bounded by
//     tanh-clip): no max-reduce, masked entries contribute exactly 0, single
//     fused load+exp+sum pass; all-masked row -> se==0 -> inv=0 (matches ref).
// B=8, R=C=200, E=256, H=16, D=16, MS_HID=32, SDIMS=2.

namespace {
constexpr int kB = 8, kH = 16;
constexpr float kCLIP = 10.f;

typedef _Float16 f16x8 __attribute__((ext_vector_type(8)));
typedef float f32x4 __attribute__((ext_vector_type(4)));
typedef int i32x4 __attribute__((ext_vector_type(4)));
typedef unsigned short us8 __attribute__((ext_vector_type(8)));
typedef unsigned int u32;
typedef unsigned long long u64;

// ---- input stream region boundaries (element index over concatenated inputs)
constexpr int B1 = 409600;    // x2
constexpr int B2 = 819200;    // cost
constexpr int B3 = 1139200;   // Wqv1
constexpr int B4 = 1270272;   // Wkv2
constexpr int B5 = 1401344;   // L1   (handled by prep branch)
constexpr int B8 = 1425936;   // o1w
constexpr int B9 = 1491472;   // o2w
constexpr int CVT_TOTAL = 1557008;
constexpr int CVT_BLOCKS = 761;   // ceil(CVT_TOTAL/8/256)
// prep work items: 1024 w1g01 + 1024 l2pack + 512 betap + 6144 vtpad + 40000 mask
constexpr int PREP_ITEMS = 48704;
constexpr int PREP_BLOCKS = 191;  // ceil(48704/256)

// ---- ws: flags then f16 heap
constexpr int FLAGS = 0;      // 16 ints
constexpr int F32_END = 16;
// f16 element offsets from hb base
constexpr int QH = 0;
constexpr int KH = 409600;
constexpr int W1G01 = 819200;         // 32 tiles x 32 lanes x 8 (dense g0/g1)
constexpr int BETAP = 827392;         // 32 tiles x 16
constexpr int L2PACK = 835584;        // 16 steps x 64 lanes x 8
constexpr int MIXA = 843776;          // 8b x 13 x 13 x 16h x 256 = 5,537,792
constexpr int MIXB = 6381568;         // 5,537,792
constexpr int X1H = 11919360;         // 409600
constexpr int X2H = 12328960;         // 409600
constexpr int WQH = 12738560;         // 131072
constexpr int WKH = 12869632;         // 131072
constexpr int VT1 = 13000704;         // 2048 rows x 224
constexpr int VT2 = 13459456;         // 2048 rows x 224
constexpr int WV1 = 13918208;         // 409600  [b][r][256]
constexpr int WV2 = 14327808;         // 409600  [b][c][256]
constexpr int O1H = 14737408;         // 65536
constexpr int O2H = 14802944;         // 65536
constexpr int COSTH = 14868480;       // 320000
constexpr int MASK1H = 15188480;      // 160000 f16 = 320000 u8: mask1[b][n][m]
constexpr int MASKTH = 15348480;      // 160000 f16 = 320000 u8: maskT[b][n][m]
constexpr size_t F16_END = 15508480;
constexpr size_t WS_NEED = (size_t)F32_END * 4 + F16_END * 2;  // ~31.0 MB

__device__ inline _Float16 f2h(float v) { return (_Float16)v; }
__device__ inline u32 pack2(float lo, float hi) {
  return (u32)__builtin_bit_cast(unsigned short, (_Float16)lo) |
         ((u32)__builtin_bit_cast(unsigned short, (_Float16)hi) << 16);
}
__device__ inline u32 pkrtz(float lo, float hi) {
  return __builtin_bit_cast(u32, __builtin_amdgcn_cvt_pkrtz(lo, hi));
}
__device__ inline float fast_tanh(float x) {
  float t = __expf(2.f * x);
  return (t - 1.f) * __builtin_amdgcn_rcpf(t + 1.f);
}
__device__ inline float rdraw(const void* s, int idx, int isbf) {
  return isbf ? __uint_as_float(((u32)((const unsigned short*)s)[idx]) << 16)
              : ((const float*)s)[idx];
}

// ---- cvt (x8 vectorized) + detect + weight pack + vt pad + mask planes -----
__global__ __launch_bounds__(256) void cvtprep_kernel(
    const void* s0, const void* s1, const void* s2, const void* s3,
    const void* s4, const void* s5, const void* s6, const void* s7,
    const void* s8, const void* s9, const unsigned char* __restrict__ mb,
    _Float16* __restrict__ hb, int* __restrict__ flags) {
  const int lane = threadIdx.x & 63;
  int bad = 0;
  const unsigned short* xp = (const unsigned short*)s0;
#pragma unroll
  for (int j = 0; j < 4; ++j) {
    float f = __uint_as_float(((u32)xp[lane * 4 + j]) << 16);
    if (!(fabsf(f) <= 1000.f)) bad = 1;  // catches NaN/inf too
  }
  const int isbf = __ballot(bad) ? 0 : 1;
  // mask element-size probe (needed by the mask-plane branch in every block)
  int nz = 0;
  for (int i = lane; i < 512; i += 64)
    if ((i & 3) && mb[i]) nz = 1;
  const int msz = __ballot(nz) ? 1 : 4;
  if (blockIdx.x == 0 && threadIdx.x == 0) { flags[0] = isbf; flags[1] = msz; }

  if (blockIdx.x < CVT_BLOCKS) {
    int i = (blockIdx.x * 256 + threadIdx.x) * 8;
    if (i >= CVT_TOTAL) return;
    const void* src;
    int off, hdst;
    if (i < B2) {
      if (i < B1) { src = s0; off = i; hdst = X1H + off; }
      else { src = s1; off = i - B1; hdst = X2H + off; }
    } else if (i < B4) {
      if (i < B3) { src = s2; off = i - B2; hdst = COSTH + off; }
      else { src = s3; off = i - B3; hdst = WQH + off; }
    } else if (i < B5) {
      src = s4; off = i - B4; hdst = WKH + off;
    } else if (i < B8) {
      return;  // L1/L2/alpha handled by prep branch
    } else {
      if (i < B9) { src = s8; off = i - B8; hdst = O1H + off; }
      else { src = s9; off = i - B9; hdst = O2H + off; }
    }
    f16x8 h;
    if (isbf) {
      us8 raw = *reinterpret_cast<const us8*>((const unsigned short*)src + off);
#pragma unroll
      for (int j = 0; j < 8; ++j)
        h[j] = f2h(__uint_as_float(((u32)raw[j]) << 16));
    } else {
      const float4* fp = reinterpret_cast<const float4*>((const float*)src + off);
      float4 a = fp[0], b = fp[1];
      h[0] = f2h(a.x); h[1] = f2h(a.y); h[2] = f2h(a.z); h[3] = f2h(a.w);
      h[4] = f2h(b.x); h[5] = f2h(b.y); h[6] = f2h(b.z); h[7] = f2h(b.w);
    }
    *reinterpret_cast<f16x8*>(hb + hdst) = h;
    return;
  }

  // ---- prep branch: packs from RAW L1/L2/alpha (s5/s6/s7) + mask planes
  int p = (blockIdx.x - CVT_BLOCKS) * 256 + threadIdx.x;
  if (p < 1024) {  // W1G01: dense g0/g1 planes [tile][lp<32][8]
    int tile = p >> 5, lp = p & 31;
    int rho = lp & 15, gg = lp >> 4;
    int k2 = tile >> 1, m = tile & 1;
    int u = k2 * 32 + 8 * (rho >> 2) + 4 * m + (rho & 3);
#pragma unroll
    for (int j = 0; j < 8; ++j) {
      int feat = 8 * gg + j;  // 0..15
      hb[W1G01 + p * 8 + j] = f2h(rdraw(s5, u * 32 + 2 * feat, isbf));
    }
  } else if (p < 2048) {  // L2PACK [k2][lane][8]
    int i2 = p - 1024;
    int k2 = i2 >> 6, l = i2 & 63;
    int head = l & 15, gg = l >> 4;
#pragma unroll
    for (int j = 0; j < 8; ++j)
      hb[L2PACK + i2 * 8 + j] = f2h(rdraw(s6, head * 512 + k2 * 32 + 8 * gg + j, isbf));
  } else if (p < 2560) {  // BETAP [tile][rho]
    int j = p - 2048;
    int tile = j >> 4, rho = j & 15;
    int k2 = tile >> 1, m = tile & 1;
    int u = k2 * 32 + 8 * (rho >> 2) + 4 * m + (rho & 3);
    float beta = 0.f;
#pragma unroll
    for (int h = 0; h < kH; ++h)
      beta += rdraw(s5, u * 32 + 2 * h + 1, isbf) * rdraw(s7, h, isbf);
    hb[BETAP + j] = f2h(beta);
  } else if (p < 8704) {  // vt zero-pad: 2048 rows x 3 f16x8 stores
    int z = p - 2560;
    int row = z / 3, j = z % 3;  // cols 200+8j (byte off 400+16j: 16B-aligned)
    const f16x8 zz = {0, 0, 0, 0, 0, 0, 0, 0};
    *reinterpret_cast<f16x8*>(hb + VT1 + row * 224 + 200 + j * 8) = zz;
    *reinterpret_cast<f16x8*>(hb + VT2 + row * 224 + 200 + j * 8) = zz;
  } else if (p < PREP_ITEMS) {  // mask planes: mask1[b][n][m], maskT[b][n][m]
    int t = p - 8704;           // 40000: b*5000 + n*25 + mgrp
    int b = t / 5000, rem = t % 5000;
    int n = rem / 25, m0 = (rem % 25) * 8;
    u64 w1 = 0, wt = 0;
    if (msz == 1) {
      w1 = *reinterpret_cast<const u64*>(mb + (size_t)b * 40000 + n * 200 + m0);
#pragma unroll
      for (int j = 0; j < 8; ++j)
        wt |= (u64)(mb[(size_t)b * 40000 + (m0 + j) * 200 + n] ? 1 : 0) << (8 * j);
    } else {
      const int* mi = (const int*)mb;
#pragma unroll
      for (int j = 0; j < 8; ++j) {
        w1 |= (u64)(mi[(size_t)b * 40000 + n * 200 + m0 + j] ? 1 : 0) << (8 * j);
        wt |= (u64)(mi[(size_t)b * 40000 + (m0 + j) * 200 + n] ? 1 : 0) << (8 * j);
      }
    }
    *reinterpret_cast<u64*>((unsigned char*)(hb + MASK1H) + (size_t)b * 40000 + n * 200 + m0) = w1;
    *reinterpret_cast<u64*>((unsigned char*)(hb + MASKTH) + (size_t)b * 40000 + n * 200 + m0) = wt;
  }
}

// ---- QKV as MFMA GEMM, both dirs via z: out = x(1600x256) @ W^T(256x512) ---
__global__ __launch_bounds__(256) void qkv_gemm_kernel(_Float16* __restrict__ hb) {
  const int z = blockIdx.z;
  const _Float16* x16 = hb + (z ? X2H : X1H);
  const _Float16* w16 = hb + (z ? WKH : WQH);
  _Float16* oqk = hb + (z ? KH : QH);
  _Float16* vt = hb + (z ? VT2 : VT1);
  const float scale = z ? 1.0f : 0.25f;
  const int l = threadIdx.x & 63;
  const int w = threadIdx.x >> 6;
  const int m0 = blockIdx.y * 16;
  const int c0 = blockIdx.x * 64 + w * 16;
  const int arow = m0 + (l & 15);
  const int bcol = c0 + (l & 15);
  const int kb = (l >> 4) * 8;
  const f16x8* ap = reinterpret_cast<const f16x8*>(x16 + (size_t)arow * 256 + kb);
  const f16x8* bp = reinterpret_cast<const f16x8*>(w16 + (size_t)bcol * 256 + kb);
  f32x4 acc = {0.f, 0.f, 0.f, 0.f};
#pragma unroll
  for (int s = 0; s < 8; ++s)
    acc = __builtin_amdgcn_mfma_f32_16x16x32_f16(ap[s * 4], bp[s * 4], acc, 0, 0, 0);
#pragma unroll
  for (int t = 0; t < 4; ++t) {
    int rr = m0 + (l >> 4) * 4 + t;
    int cc = c0 + (l & 15);
    int b = rr / 200, r = rr - b * 200;
    if (cc < 256) {
      oqk[((b * 16 + (cc >> 4)) * 200 + r) * 16 + (cc & 15)] = f2h(scale * acc[t]);
    } else {
      int h = (cc - 256) >> 4, d = (cc - 256) & 15;
      vt[(size_t)((b * 16 + h) * 16 + d) * 224 + r] = f2h(acc[t]);
    }
  }
}

// ---- MFMA mixed kernel: 4 waves/block, W1 in block LDS, tanh'd outputs -----
__global__ __launch_bounds__(256) void mixed_mfma_kernel(_Float16* __restrict__ hb) {
  __shared__ _Float16 wlds[8192];             // [32 tiles][32 lanes][8]
  __shared__ _Float16 betalds[512];           // [32 tiles][16 rho]
  __shared__ _Float16 scores[4096];           // [r16][p16][f16], XOR-swizzled
  __shared__ _Float16 mixtile[16 * 16 * 24];  // [h][c][r pad 24]

  const int tid = threadIdx.x;
  const int l = tid & 63;
  const int wv = tid >> 6;
  const int p = l & 15;
  const int g = l >> 4;
  const int b = blockIdx.z;
  const int rt = blockIdx.y, ct = blockIdx.x;
  const int r0 = rt * 16, c0 = ct * 16;
  const f32x4 fzero = {0.f, 0.f, 0.f, 0.f};
  const f16x8 hzero = {0, 0, 0, 0, 0, 0, 0, 0};
  const _Float16* qh = hb + QH;
  const _Float16* kh = hb + KH;
  const _Float16* costh = hb + COSTH;

  // stage W1 planes + beta into LDS (block-shared)
  {
    const f16x8* src = reinterpret_cast<const f16x8*>(hb + W1G01);
    f16x8* dst = reinterpret_cast<f16x8*>(wlds);
#pragma unroll
    for (int i = 0; i < 4; ++i) dst[i * 256 + tid] = src[i * 256 + tid];
    reinterpret_cast<u32*>(betalds)[tid] =
        reinterpret_cast<const u32*>(hb + BETAP)[tid];
  }

  // L2 fragments in registers (64 VGPR, per-wave; indices ALL compile-time)
  f16x8 l2f[16];
  {
    const f16x8* lp2 = reinterpret_cast<const f16x8*>(hb + L2PACK) + l;
#pragma unroll
    for (int t = 0; t < 16; ++t) l2f[t] = lp2[t * 64];
  }

  // ---- QK phase: this wave computes its 4 heads (hc = wv)
  int qrow = r0 + p; if (qrow > 199) qrow = 199;
  int krow = c0 + p; if (krow > 199) krow = 199;
  {
    const int hc = wv;
    f32x4 acc[4];
#pragma unroll
    for (int i = 0; i < 4; ++i) {
      int h = hc * 4 + i;
      f16x8 qf = hzero, kf = hzero;
      if (g < 2) {
        qf = *reinterpret_cast<const f16x8*>(qh + ((b * 16 + h) * 200 + qrow) * 16 + 8 * g);
        kf = *reinterpret_cast<const f16x8*>(kh + ((b * 16 + h) * 200 + krow) * 16 + 8 * g);
      }
      acc[i] = __builtin_amdgcn_mfma_f32_16x16x32_f16(qf, kf, fzero, 0, 0, 0);
    }
#pragma unroll
    for (int pr = 0; pr < 2; ++pr) {
      int h = hc * 4 + pr * 2;
#pragma unroll
      for (int t = 0; t < 4; ++t) {
        u32 pk = pack2(acc[pr * 2][t], acc[pr * 2 + 1][t]);
        u32 a = (u32)((4 * g + t) * 512 + p * 32 + h * 2) ^ (((p >> 2) & 3) << 4);
        *reinterpret_cast<u32*>(reinterpret_cast<char*>(scores) + a) = pk;
      }
    }
  }
  __syncthreads();  // covers weight staging + scores

  // ---- main loop: rows r = wv*4 + {0..3}, 2 chains x 2 split accumulators.
  // k2 loop FULLY unrolled (rule #20: l2f[k2] runtime-indexed would spill).
  int ccol = c0 + p; if (ccol > 199) ccol = 199;
#pragma unroll
  for (int rr = 0; rr < 4; rr += 2) {
    const int rA = wv * 4 + rr, rB = rA + 1;
    u32 aA = (u32)(rA * 512 + p * 32 + (g & 1) * 16) ^ (((p >> 2) & 3) << 4);
    u32 aB = (u32)(rB * 512 + p * 32 + (g & 1) * 16) ^ (((p >> 2) & 3) << 4);
    f16x8 sfA = *reinterpret_cast<const f16x8*>(reinterpret_cast<char*>(scores) + aA);
    f16x8 sfB = *reinterpret_cast<const f16x8*>(reinterpret_cast<char*>(scores) + aB);
    int rrA = r0 + rA; if (rrA > 199) rrA = 199;
    int rrB = r0 + rB; if (rrB > 199) rrB = 199;
    _Float16 cvA = costh[(b * 200 + rrA) * 200 + ccol];
    _Float16 cvB = costh[(b * 200 + rrB) * 200 + ccol];
    f16x8 bfA, bfB;
    if (g < 2) { bfA = sfA; bfB = sfB; }
    else if (g == 2) {
      bfA = hzero; bfA[0] = cvA;
      bfB = hzero; bfB[0] = cvB;
    } else { bfA = hzero; bfB = hzero; }

    f32x4 mA0 = fzero, mA1 = fzero, mB0 = fzero, mB1 = fzero;
#pragma unroll
    for (int k2 = 0; k2 < 16; ++k2) {
      f16x8 w1a, w1b;
      if (l < 32) {
        w1a = *reinterpret_cast<const f16x8*>(&wlds[(2 * k2) * 256 + l * 8]);
        w1b = *reinterpret_cast<const f16x8*>(&wlds[(2 * k2 + 1) * 256 + l * 8]);
      } else if (g == 2) {
        w1a = hzero; w1a[0] = betalds[(2 * k2) * 16 + p];
        w1b = hzero; w1b[0] = betalds[(2 * k2 + 1) * 16 + p];
      } else { w1a = hzero; w1b = hzero; }

      f32x4 h0A = __builtin_amdgcn_mfma_f32_16x16x32_f16(w1a, bfA, fzero, 0, 0, 0);
      f32x4 h1A = __builtin_amdgcn_mfma_f32_16x16x32_f16(w1b, bfA, fzero, 0, 0, 0);
      f32x4 h0B = __builtin_amdgcn_mfma_f32_16x16x32_f16(w1a, bfB, fzero, 0, 0, 0);
      f32x4 h1B = __builtin_amdgcn_mfma_f32_16x16x32_f16(w1b, bfB, fzero, 0, 0, 0);
      // convert-then-relu: RTZ is monotone, so max(cvt(x),0) == cvt(max(x,0))
      i32x4 piA = {(int)pkrtz(h0A[0], h0A[1]), (int)pkrtz(h0A[2], h0A[3]),
                   (int)pkrtz(h1A[0], h1A[1]), (int)pkrtz(h1A[2], h1A[3])};
      i32x4 piB = {(int)pkrtz(h0B[0], h0B[1]), (int)pkrtz(h0B[2], h0B[3]),
                   (int)pkrtz(h1B[0], h1B[1]), (int)pkrtz(h1B[2], h1B[3])};
      f16x8 pa = __builtin_elementwise_max(__builtin_bit_cast(f16x8, piA), hzero);
      f16x8 pb = __builtin_elementwise_max(__builtin_bit_cast(f16x8, piB), hzero);
      if (k2 & 1) {
        mA1 = __builtin_amdgcn_mfma_f32_16x16x32_f16(l2f[k2], pa, mA1, 0, 0, 0);
        mB1 = __builtin_amdgcn_mfma_f32_16x16x32_f16(l2f[k2], pb, mB1, 0, 0, 0);
      } else {
        mA0 = __builtin_amdgcn_mfma_f32_16x16x32_f16(l2f[k2], pa, mA0, 0, 0, 0);
        mB0 = __builtin_amdgcn_mfma_f32_16x16x32_f16(l2f[k2], pb, mB0, 0, 0, 0);
      }
    }
    f32x4 mA = mA0 + mA1, mB = mB0 + mB1;
    // fused tanh*CLIP: computed ONCE here, shared by both combine directions
#pragma unroll
    for (int t = 0; t < 4; ++t) {
      int h = 4 * g + t;
      mixtile[(h * 16 + p) * 24 + rA] = f2h(fast_tanh(mA[t]) * kCLIP);
      mixtile[(h * 16 + p) * 24 + rB] = f2h(fast_tanh(mB[t]) * kCLIP);
    }
  }
  __syncthreads();

  // ---- block-contiguous copy-out: one wave-instruction = 1KB consecutive ---
  // MIXA region [b][rt][ct] -> [h][n=r][m=c]; MIXB region [b][ct][rt] -> [h][m][n]
  {
    _Float16* regA = hb + MIXA + ((size_t)((b * 13 + rt) * 13 + ct)) * 4096;
    _Float16* regB = hb + MIXB + ((size_t)((b * 13 + ct) * 13 + rt)) * 4096;
#pragma unroll
    for (int k = 0; k < 2; ++k) {
      int e = k * 2048 + tid * 8;
      int h = e >> 8, rem = e & 255;
      int n = rem >> 4, m0 = rem & 15;  // m0 in {0,8}
      f16x8 va;
#pragma unroll
      for (int j = 0; j < 8; ++j) va[j] = mixtile[(h * 16 + m0 + j) * 24 + n];
      *reinterpret_cast<f16x8*>(regA + e) = va;
    }
#pragma unroll
    for (int k = 0; k < 2; ++k) {
      int e = k * 2048 + tid * 8;
      int h = e >> 8, rem = e & 255;
      int m = rem >> 4, n0 = rem & 15;  // n0 in {0,8}, 16B-aligned (pad 24)
      f16x8 vb = *reinterpret_cast<const f16x8*>(&mixtile[(h * 16 + m) * 24 + n0]);
      *reinterpret_cast<f16x8*>(regB + e) = vb;
    }
  }
}

// ---- fused softmax + P@vT: 4 waves/block (4 heads), barrier-free ------------
// grid (13 ntile, 4 hgroup, 16 = dir*8+b). logits are pre-tanh'd (|x|<=10):
// constant-shift softmax exp(x-10); masked -> 0; all-masked -> se=0 -> inv=0.
__global__ __launch_bounds__(256) void fused_combine_kernel(
    _Float16* __restrict__ hb, const int* __restrict__ flags) {
  __shared__ _Float16 wt[4][16 * 256];  // per-wave 8KB chunk, XOR-swizzled rows
  const int z = blockIdx.z;
  const int dir = z >> 3, b = z & 7;
  const _Float16* lt = hb + (dir ? MIXB : MIXA);
  const _Float16* vt = hb + (dir ? VT1 : VT2);
  _Float16* wv = hb + (dir ? WV2 : WV1);
  const unsigned char* mplane =
      (const unsigned char*)(hb + (dir ? MASKTH : MASK1H));
  const int wvid = threadIdx.x >> 6;
  const int l = threadIdx.x & 63;
  const int row = l & 15, grp = l >> 4;
  const int r0 = blockIdx.x * 16;
  const int h = blockIdx.y * 4 + wvid;
  const int bh = b * 16 + h;
  int n = r0 + row; if (n > 199) n = 199;  // clamp for mask only
  // tiled logits: [b][ntile][mtile][h][n_in=row][m_in]
  const _Float16* lgt = lt + (size_t)(b * 13 + blockIdx.x) * 53248 + h * 256 + row * 16;
  const unsigned char* mk = mplane + (size_t)b * 40000 + n * 200;
  char* wtb = reinterpret_cast<char*>(wt[wvid]);

  float xv[7][8];
  float se = 0.f;
#pragma unroll
  for (int i = 0; i < 7; ++i) {
    int c0 = grp * 8 + i * 32;
    if (c0 < 200) {  // c0 multiple of 8 -> c0+7 <= 199
      f16x8 lv = *reinterpret_cast<const f16x8*>(lgt + (c0 >> 4) * 4096 + (c0 & 15));
      u64 mv = *reinterpret_cast<const u64*>(mk + c0);
#pragma unroll
      for (int j = 0; j < 8; ++j) {
        bool mskd = ((mv >> (8 * j)) & 0xffull) != 0;
        float e = mskd ? 0.f : __expf((float)lv[j] - kCLIP);
        xv[i][j] = e;
        se += e;
      }
    } else {
#pragma unroll
      for (int j = 0; j < 8; ++j) xv[i][j] = 0.f;
    }
  }
  se += __shfl_xor(se, 16);
  se += __shfl_xor(se, 32);
  float inv = (se > 0.f) ? 1.f / se : 0.f;  // all-masked row -> zero weights
#pragma unroll
  for (int i = 0; i < 7; ++i) {
    int c0 = grp * 8 + i * 32;
    f16x8 pv;
#pragma unroll
    for (int j = 0; j < 8; ++j) pv[j] = f2h(xv[i][j] * inv);
    u32 a = (u32)(row * 512 + c0 * 2) ^ (u32)((row & 7) << 4);
    *reinterpret_cast<f16x8*>(wtb + a) = pv;
  }
  // no barrier: wt chunk is written and read by this wave only (lgkmcnt order)

  f32x4 acc = {0.f, 0.f, 0.f, 0.f};
#pragma unroll
  for (int k2 = 0; k2 < 7; ++k2) {
    int kb = k2 * 32 + grp * 8;
    u32 a = (u32)(row * 512 + kb * 2) ^ (u32)((row & 7) << 4);
    f16x8 af = *reinterpret_cast<const f16x8*>(wtb + a);
    f16x8 bf = *reinterpret_cast<const f16x8*>(vt + (size_t)(bh * 16 + row) * 224 + kb);
    acc = __builtin_amdgcn_mfma_f32_16x16x32_f16(af, bf, acc, 0, 0, 0);
  }
#pragma unroll
  for (int t = 0; t < 4; ++t) {
    int r = r0 + grp * 4 + t;
    if (r < 200)
      wv[((size_t)b * 200 + r) * 256 + h * 16 + row] = f2h(acc[t]);
  }
}

// ---- out = wv(1600x256) @ Wout^T(256x256), both dirs via z ------------------
__global__ __launch_bounds__(256) void out_gemm_kernel(
    const _Float16* __restrict__ hb, void* __restrict__ out,
    const int* __restrict__ flags) {
  const int z = blockIdx.z;
  const _Float16* wvh = hb + (z ? WV2 : WV1);
  const _Float16* wout = hb + (z ? O2H : O1H);
  const int outOff = z ? 409600 : 0;
  const int l = threadIdx.x & 63;
  const int w = threadIdx.x >> 6;
  const int m0 = blockIdx.y * 16;
  const int c0 = blockIdx.x * 64 + w * 16;
  const int arow = m0 + (l & 15);
  const int bcol = c0 + (l & 15);
  const int kb = (l >> 4) * 8;
  const f16x8* ap = reinterpret_cast<const f16x8*>(wvh + (size_t)arow * 256 + kb);
  const f16x8* bp = reinterpret_cast<const f16x8*>(wout + (size_t)bcol * 256 + kb);
  f32x4 acc = {0.f, 0.f, 0.f, 0.f};
#pragma unroll
  for (int s = 0; s < 8; ++s)
    acc = __builtin_amdgcn_mfma_f32_16x16x32_f16(ap[s * 4], bp[s * 4], acc, 0, 0, 0);
  int isbf = flags[0];
#pragma unroll
  for (int t = 0; t < 4; ++t) {
    size_t oidx = (size_t)outOff + (size_t)(m0 + (l >> 4) * 4 + t) * 256 + c0 + (l & 15);
    if (isbf) ((__hip_bfloat16*)out)[oidx] = __float2bfloat16(acc[t]);
    else ((float*)out)[oidx] = acc[t];
  }
}

}  // namespace

extern "C" void kernel_launch(void* const* d_in, const int* in_sizes, int n_in,
                              void* d_out, int out_size, void* d_ws, size_t ws_size,
                              hipStream_t stream) {
  if (ws_size < WS_NEED) return;  // output stays zero -> loud failure
  const unsigned char* mask = (const unsigned char*)d_in[2];

  float* ws = (float*)d_ws;
  _Float16* hb = (_Float16*)(ws + F32_END);
  int* flags = (int*)(ws + FLAGS);

  cvtprep_kernel<<<dim3(CVT_BLOCKS + PREP_BLOCKS), 256, 0, stream>>>(
      d_in[0], d_in[1], d_in[3], d_in[4], d_in[5], d_in[6], d_in[7], d_in[8],
      d_in[9], d_in[10], mask, hb, flags);
  qkv_gemm_kernel<<<dim3(8, 100, 2), 256, 0, stream>>>(hb);
  mixed_mfma_kernel<<<dim3(13, 13, kB), 256, 0, stream>>>(hb);
  fused_combine_kernel<<<dim3(13, 4, 16), 256, 0, stream>>>(hb, flags);
  out_gemm_kernel<<<dim3(4, 100, 2), 256, 0, stream>>>(hb, d_out, flags);
}